// Round 6
// baseline (13.597 us; speedup 1.0000x reference)
//
#include <hip/hip_runtime.h>
#include <cfloat>

#define HH 128
#define BB 128
#define AA 243
#define MAXV 9

typedef float v2f __attribute__((ext_vector_type(2)));

__device__ __forceinline__ int rli(float x, int l) {
    return __builtin_amdgcn_readlane(__builtin_bit_cast(int, x), l);
}
__device__ __forceinline__ float rl(float x, int l) {
    return __builtin_bit_cast(float, __builtin_amdgcn_readlane(__builtin_bit_cast(int, x), l));
}
__device__ __forceinline__ unsigned long long pack2(int lo, int hi) {
    int2 p; p.x = lo; p.y = hi;
    return __builtin_bit_cast(unsigned long long, p);  // REG_SEQUENCE: no ALU cost
}
// acc = broadcast(sv.lo) * w + acc   (packed 2xf32, scalar broadcast from SGPR pair)
__device__ __forceinline__ void pk_fma_lo(v2f& acc, unsigned long long sv, v2f w) {
    asm("v_pk_fma_f32 %0, %2, %1, %0 op_sel:[0,0,0] op_sel_hi:[0,1,1]"
        : "+v"(acc) : "v"(w), "s"(sv));
}
// acc = broadcast(sv.hi) * w + acc
__device__ __forceinline__ void pk_fma_hi(v2f& acc, unsigned long long sv, v2f w) {
    asm("v_pk_fma_f32 %0, %2, %1, %0 op_sel:[1,0,0] op_sel_hi:[1,1,1]"
        : "+v"(acc) : "v"(w), "s"(sv));
}

// Per-wave GEMV quarter: NV node rows, 32-wide h-slice, 2 adjacent cols/thread.
template<int NV, bool PRED>
__device__ __forceinline__ void gemv_phase(
    const float* __restrict__ nf, int off, int v, int hbase,
    bool write_rd, float* __restrict__ rdbuf,
    const v2f* __restrict__ wreg, float* __restrict__ dst, int c0)
{
    float rr[NV]; float rdsum = 0.f;
    #pragma unroll
    for (int i = 0; i < NV; ++i) {
        float x = PRED ? ((i < v) ? nf[(off + i) * HH + hbase] : 0.f)
                       : nf[(off + i) * HH + hbase];
        rdsum += x;                  // raw (pre-relu) for readout
        rr[i] = fmaxf(x, 0.f);
    }
    if (write_rd) rdbuf[hbase] = rdsum;
    v2f acc[NV];
    #pragma unroll
    for (int i = 0; i < NV; ++i) acc[i] = (v2f)(0.0f);
    #pragma unroll
    for (int h = 0; h < 32; h += 2) {
        const v2f w0 = wreg[h], w1 = wreg[h + 1];
        #pragma unroll
        for (int i = 0; i < NV; ++i) {
            unsigned long long sv = pack2(rli(rr[i], h), rli(rr[i], h + 1));
            pk_fma_lo(acc[i], sv, w0);
            pk_fma_hi(acc[i], sv, w1);
        }
    }
    #pragma unroll
    for (int i = 0; i < NV; ++i) *(v2f*)(dst + i * 132 + c0) = acc[i];
}

__global__ __launch_bounds__(512) void apm_fused(
    const float* __restrict__ nf,        // (N,H)
    const float* __restrict__ maskp,     // (B,A)
    const float* __restrict__ W_fcv1,    // (H,64)
    const float* __restrict__ b_fcv1,    // (64)
    const float* __restrict__ W_fcv2,    // (64,1)
    const float* __restrict__ b_fcv2,    // (1)
    const float* __restrict__ W_a2,      // (2H,H)
    const float* __restrict__ b_a2,      // (H)
    const float* __restrict__ W_final,   // (H,3)
    const float* __restrict__ b_final,   // (3)
    const int*   __restrict__ indexmask, // (B,A)
    const int*   __restrict__ bnn,       // (B)
    float* __restrict__ probs_out,       // (B,A)
    float* __restrict__ readout_out)     // (B,1)
{
    const int b    = blockIdx.x;
    const int t    = threadIdx.x;
    const int lane = t & 63;
    const int w    = t >> 6;
    const int matB = w >> 2;        // 0 -> Ai (W_a2[:H]), 1 -> Bj (W_a2[H:])
    const int hq   = w & 3;         // 32-wide h-quarter this wave reduces
    const int c0   = lane << 1;     // two adjacent columns per thread

    __shared__ float pS[2][4][MAXV][132];  // [mat][h-quarter][i][col]
    __shared__ float wfT[3][HH];           // W_final transposed
    __shared__ float rdbuf[HH];            // segment-sum (pre-relu)
    __shared__ float rout[64];             // readout hi-half partial
    __shared__ float2 xr2[8];              // per-wave (max, sum) for softmax

    // ---- bnn first: heads the longest chain (off -> nf -> GEMV) ----
    int ov = 0;
    if (lane < b)      ov += bnn[lane];
    if (lane + 64 < b) ov += bnn[lane + 64];
    const int v = bnn[b];                  // uniform

    // ---- W_a2 slice -> 32 v2f registers (independent; hides under bnn chain) ----
    const float* Wb = W_a2 + matB * (HH * HH) + (hq * 32) * HH + c0;
    v2f wreg[32];
    #pragma unroll
    for (int h = 0; h < 32; ++h) wreg[h] = *(const v2f*)(Wb + h * HH);

    // ---- early loads + gather-order score decode (scores computed in
    //      indexmask order => no sc buffer, no reorder barrier) ----
    float mk = 0.f, bfin = 0.f;
    int im = 0, pi = 0, pj = 0, pk = 0;
    if (t < AA) {
        im   = indexmask[b * AA + t];
        mk   = maskp[b * AA + t];
        pk   = im % 3;
        int pair = im / 3;
        if (v == 8) { pi = pair >> 3; pj = pair & 7; }       // uniform branch
        else        { pi = pair / v;  pj = pair - pi * v; }
        pi = min(pi, MAXV - 1); pj = min(pj, MAXV - 1);      // clamp discarded lanes
        bfin = b_final[pk];
    }
    if (t < 3 * HH) {
        int h = t / 3, k = t - 3 * h;
        wfT[k][h] = W_final[t];
    }

    // ---- graph offset: per-wave shuffle reduce ----
    #pragma unroll
    for (int o = 1; o < 64; o <<= 1) ov += __shfl_xor(ov, o, 64);
    const int off = ov;

    // ---- GEMV quarter (v==8 fast path removes predication + 9th row) ----
    const int hbase = hq * 32 + (lane & 31);
    const bool wrd  = (w < 4) && (lane < 32);
    float* dst = &pS[matB][hq][0][0];
    if (v == 8) gemv_phase<8, false>(nf, off, v, hbase, wrd, rdbuf, wreg, dst, c0);
    else        gemv_phase<MAXV, true>(nf, off, v, hbase, wrd, rdbuf, wreg, dst, c0);
    __syncthreads();                                   // barrier 1

    float a2lo = 0.f;                      // wave-7 readout partial (reg across barrier)
    if (w < 6) {
        // ---- combine 4 h-quarter partials; fold b_a2 into A (waves 0-5) ----
        #pragma unroll
        for (int rep = 0; rep < 3; ++rep) {
            int idx = t + rep * 384;       // 2 mats x 9 i x 64 float2-cols = 1152
            int m   = idx / 576;
            int rem = idx - m * 576;
            int i   = rem >> 6;
            int cc  = (rem & 63) << 1;
            float2 p0 = *(const float2*)&pS[m][0][i][cc];
            float2 p1 = *(const float2*)&pS[m][1][i][cc];
            float2 p2 = *(const float2*)&pS[m][2][i][cc];
            float2 p3 = *(const float2*)&pS[m][3][i][cc];
            float sx = (p0.x + p1.x) + (p2.x + p3.x);
            float sy = (p0.y + p1.y) + (p2.y + p3.y);
            if (m == 0) { sx += b_a2[cc]; sy += b_a2[cc + 1]; }
            *(float2*)&pS[m][0][i][cc] = make_float2(sx, sy);
        }
    } else if (w == 6) {
        // ---- readout hi-half partial (4 independent chains) ----
        float rd1 = rdbuf[64 + lane];
        float q0 = 0.f, q1 = 0.f, q2 = 0.f, q3 = 0.f;
        #pragma unroll
        for (int h = 0; h < 16; ++h) {
            q0 = fmaf(rl(rd1, h),      W_fcv1[(64 + h)  * 64 + lane], q0);
            q1 = fmaf(rl(rd1, h + 16), W_fcv1[(80 + h)  * 64 + lane], q1);
            q2 = fmaf(rl(rd1, h + 32), W_fcv1[(96 + h)  * 64 + lane], q2);
            q3 = fmaf(rl(rd1, h + 48), W_fcv1[(112 + h) * 64 + lane], q3);
        }
        rout[lane] = (q0 + q1) + (q2 + q3);
    } else {
        // ---- readout lo-half partial (stays in register) ----
        float rd0 = rdbuf[lane];
        float q0 = b_fcv1[lane], q1 = 0.f, q2 = 0.f, q3 = 0.f;
        #pragma unroll
        for (int h = 0; h < 16; ++h) {
            q0 = fmaf(rl(rd0, h),      W_fcv1[h        * 64 + lane], q0);
            q1 = fmaf(rl(rd0, h + 16), W_fcv1[(16 + h) * 64 + lane], q1);
            q2 = fmaf(rl(rd0, h + 32), W_fcv1[(32 + h) * 64 + lane], q2);
            q3 = fmaf(rl(rd0, h + 48), W_fcv1[(48 + h) * 64 + lane], q3);
        }
        a2lo = (q0 + q1) + (q2 + q3);
    }
    __syncthreads();                                   // barrier 2

    // ---- score in gather order (waves 0-3) ∥ readout finish (wave 7) ----
    float x = -FLT_MAX;
    if (t < AA) {
        const float* ar = &pS[0][0][pi][0];
        const float* br = &pS[1][0][pj][0];
        const float* wk = &wfT[pk][0];
        float s0 = 0.f, s1 = 0.f, s2 = 0.f, s3 = 0.f;
        #pragma unroll 8
        for (int h = 0; h < HH; h += 4) {
            float4 a4 = *(const float4*)(ar + h);
            float4 b4 = *(const float4*)(br + h);
            float4 w4 = *(const float4*)(wk + h);
            s0 = fmaf(fmaxf(a4.x + b4.x, 0.f), w4.x, s0);
            s1 = fmaf(fmaxf(a4.y + b4.y, 0.f), w4.y, s1);
            s2 = fmaf(fmaxf(a4.z + b4.z, 0.f), w4.z, s2);
            s3 = fmaf(fmaxf(a4.w + b4.w, 0.f), w4.w, s3);
        }
        float s = bfin + ((s0 + s1) + (s2 + s3));
        x = (im < v * v * 3) ? s + mk : mk;   // invalid entries gather 0 (+mask)
    } else if (w == 7) {
        float a2 = a2lo + rout[lane];
        float xr = fmaxf(a2, 0.f) * W_fcv2[lane];
        #pragma unroll
        for (int o = 1; o < 64; o <<= 1) xr += __shfl_xor(xr, o, 64);
        if (lane == 0) readout_out[b] = xr + b_fcv2[0];
    }

    // ---- online softmax: per-wave (m,s), one cross-wave barrier ----
    float m_w = x;
    #pragma unroll
    for (int o = 1; o < 64; o <<= 1) m_w = fmaxf(m_w, __shfl_xor(m_w, o, 64));
    float e = (t < AA) ? __expf(x - m_w) : 0.f;
    float s_w = e;
    #pragma unroll
    for (int o = 1; o < 64; o <<= 1) s_w += __shfl_xor(s_w, o, 64);
    if (lane == 0 && w < 4) xr2[w] = make_float2(m_w, s_w);
    __syncthreads();                                   // barrier 3
    if (t < AA) {
        float2 p0 = xr2[0], p1 = xr2[1], p2 = xr2[2], p3 = xr2[3];
        float m = fmaxf(fmaxf(p0.x, p1.x), fmaxf(p2.x, p3.x));
        float denom = p0.y * __expf(p0.x - m) + p1.y * __expf(p1.x - m)
                    + p2.y * __expf(p2.x - m) + p3.y * __expf(p3.x - m);
        float f = __expf(m_w - m);
        probs_out[b * AA + t] = e * f * __builtin_amdgcn_rcpf(denom);
    }
}

extern "C" void kernel_launch(void* const* d_in, const int* in_sizes, int n_in,
                              void* d_out, int out_size, void* d_ws, size_t ws_size,
                              hipStream_t stream) {
    const float* nf      = (const float*)d_in[0];
    // d_in[1] = len_vec (==1 for in-graph pairs) -> unused
    const float* maskp   = (const float*)d_in[2];
    const float* W_fcv1  = (const float*)d_in[3];
    const float* b_fcv1  = (const float*)d_in[4];
    const float* W_fcv2  = (const float*)d_in[5];
    const float* b_fcv2  = (const float*)d_in[6];
    const float* W_a2    = (const float*)d_in[7];
    const float* b_a2    = (const float*)d_in[8];
    const float* W_final = (const float*)d_in[9];
    const float* b_final = (const float*)d_in[10];
    const int*   indexmask = (const int*)d_in[11];
    // d_in[12] = segment_ids (contiguous blocks) -> offsets derived from bnn
    const int*   bnn       = (const int*)d_in[13];

    float* probs   = (float*)d_out;
    float* readout = probs + BB * AA;

    apm_fused<<<BB, 512, 0, stream>>>(nf, maskp, W_fcv1, b_fcv1, W_fcv2, b_fcv2,
                                      W_a2, b_a2, W_final, b_final,
                                      indexmask, bnn, probs, readout);
}